// Round 6
// baseline (338.145 us; speedup 1.0000x reference)
//
#include <hip/hip_runtime.h>

#define N_NODES 50000
#define N_EDGES 800000
#define NPAD 50176   // 49 * 1024, padded histogram size

typedef float f32x4 __attribute__((ext_vector_type(4)));
typedef short bf16x8 __attribute__((ext_vector_type(8)));

__device__ __forceinline__ float fast_tanh(float x) {
  // tanh(x) = 1 - 2/(exp(2x)+1); v_rcp_f32 (1 ulp) instead of IEEE div sequence
  float e = __expf(2.0f * x);
  float r;
  asm("v_rcp_f32 %0, %1" : "=v"(r) : "v"(e + 1.0f));
  return fmaf(-2.0f, r, 1.0f);
}

__device__ __forceinline__ unsigned short f2bf_rne(float x) {
  unsigned u = __float_as_uint(x);
  unsigned r = u + 0x7FFFu + ((u >> 16) & 1u);
  return (unsigned short)(r >> 16);
}

// ---------- fused hist + prep.  Blocks [0,3125): histogram of idx_j.
// Blocks [3125, 3302): prep work (Bpack / W12 / b12 / W2pack).
__global__ __launch_bounds__(256) void hist_prep_kernel(
    const int* __restrict__ idx_j,
    const float* __restrict__ piW1, const float* __restrict__ pib1,
    const float* __restrict__ piW2, const float* __restrict__ pib2,
    const float* __restrict__ piW3, const float* __restrict__ iiW1,
    const float* __restrict__ iiW2,
    int* __restrict__ counts,
    float* __restrict__ W12, float* __restrict__ b12,
    unsigned short* __restrict__ Bpack, unsigned short* __restrict__ W2pack) {
  int bid = blockIdx.x;
  if (bid < 3125) {
    int e = bid * 256 + threadIdx.x;
    if (e < N_EDGES) atomicAdd(&counts[idx_j[e]], 1);
    return;
  }
  int gid = (bid - 3125) * 256 + threadIdx.x;
  if (gid < 32768) {
    // Bpack[ks][ct][lane][j] = bf16(W3i[kidx][col]); W3i[kidx][c]=sum_m piW3[k][m*8+b]*iiW1[m][c]
    int j = gid & 7;
    int lane = (gid >> 3) & 63;
    int ct = (gid >> 9) & 3;
    int ks = gid >> 11;
    int kidx = ks * 32 + ((lane >> 4) << 3) + j;
    int col = ct * 16 + (lane & 15);
    int k = kidx >> 3, b = kidx & 7;
    float acc = 0.f;
    #pragma unroll 8
    for (int mm = 0; mm < 64; ++mm)
      acc = fmaf(piW3[k * 512 + mm * 8 + b], iiW1[mm * 64 + col], acc);
    Bpack[gid] = f2bf_rne(acc);
  } else if (gid < 41024) {
    int g1 = gid - 32768;
    if (g1 < 8192) {
      int m = g1 >> 6, c = g1 & 63;
      float acc = 0.f;
      #pragma unroll 8
      for (int k = 0; k < 64; ++k) acc = fmaf(piW1[m * 64 + k], piW2[k * 64 + c], acc);
      W12[g1] = acc;
    } else {
      int c = g1 - 8192;
      float acc = pib2[c];
      for (int k = 0; k < 64; ++k) acc = fmaf(pib1[k], piW2[k * 64 + c], acc);
      b12[c] = acc;
    }
  } else if (gid < 45120) {
    int g2 = gid - 41024;
    int j = g2 & 7;
    int lane = (g2 >> 3) & 63;
    int ct = (g2 >> 9) & 3;
    int ks = g2 >> 11;
    int kidx = ks * 32 + ((lane >> 4) << 3) + j;
    int col = ct * 16 + (lane & 15);
    W2pack[g2] = f2bf_rne(iiW2[kidx * 64 + col]);
  }
}

// ---------- single-dispatch exclusive scan: block b scans chunk b, and computes its
// base by redundantly summing all counts of preceding chunks (<=48K loads, trivial).
__global__ __launch_bounds__(1024) void scan_kernel(
    const int* __restrict__ counts, int* __restrict__ cursors) {
  __shared__ int buf[1024];
  __shared__ int red[16];
  int b = blockIdx.x, tid = threadIdx.x;
  int idx = b * 1024 + tid;
  int v = counts[idx];
  buf[tid] = v;
  int partial = 0;
  for (int i = tid; i < b * 1024; i += 1024) partial += counts[i];
  #pragma unroll
  for (int off = 32; off >= 1; off >>= 1) partial += __shfl_down(partial, off, 64);
  if ((tid & 63) == 0) red[tid >> 6] = partial;
  __syncthreads();
  for (int off = 1; off < 1024; off <<= 1) {
    int t = (tid >= off) ? buf[tid - off] : 0;
    __syncthreads();
    buf[tid] += t;
    __syncthreads();
  }
  int base = 0;
  #pragma unroll
  for (int i = 0; i < 16; ++i) base += red[i];
  cursors[idx] = base + buf[tid] - v;
}

// ---------- scatter edges into j-sorted order; record = (orig_edge, j)
__global__ __launch_bounds__(256) void sort_scatter_kernel(
    const int* __restrict__ idx_j, int* __restrict__ cursors,
    int2* __restrict__ sorted_ej) {
  int e = blockIdx.x * 256 + threadIdx.x;
  if (e < N_EDGES) {
    int j = idx_j[e];
    int pos = atomicAdd(&cursors[j], 1);
    sorted_ej[pos] = make_int2(e, j);
  }
}

// ---------- node: p1 = tanh(p@ppW1+b1)@ppW2+b2 ; qa = p1@W12[0:64]; qb = p1@W12[64:128]
__global__ __launch_bounds__(256) void node_kernel(
    const float* __restrict__ p,
    const float* __restrict__ ppW1, const float* __restrict__ ppb1,
    const float* __restrict__ ppW2, const float* __restrict__ ppb2,
    const float* __restrict__ W12,
    float* __restrict__ qa, float* __restrict__ qb) {
  __shared__ float sW1[64 * 64];
  __shared__ float sW2[64 * 64];
  __shared__ float sW12[128 * 64];
  __shared__ float sb1[64], sb2[64];
  __shared__ float sX[4][8][64];
  int tid = threadIdx.x;
  for (int i = tid; i < 64 * 64; i += 256) { sW1[i] = ppW1[i]; sW2[i] = ppW2[i]; }
  for (int i = tid; i < 128 * 64; i += 256) sW12[i] = W12[i];
  if (tid < 64) { sb1[tid] = ppb1[tid]; sb2[tid] = ppb2[tid]; }
  __syncthreads();
  int wave = tid >> 6, lane = tid & 63;
  int rowbase = blockIdx.x * 32 + wave * 8;

  float4* sXf4 = (float4*)&sX[wave][0][0];
  for (int t = lane; t < 128; t += 64) {
    int r = t >> 4, c4 = t & 15;
    int row = rowbase + r;
    float4 v = make_float4(0.f, 0.f, 0.f, 0.f);
    if (row < N_NODES) v = ((const float4*)p)[row * 16 + c4];
    sXf4[t] = v;
  }
  __syncthreads();

  float h[8];
  #pragma unroll
  for (int r = 0; r < 8; ++r) h[r] = sb1[lane];
  for (int k = 0; k < 64; ++k) {
    float w = sW1[k * 64 + lane];
    #pragma unroll
    for (int r = 0; r < 8; ++r) h[r] = fmaf(sX[wave][r][k], w, h[r]);
  }
  #pragma unroll
  for (int r = 0; r < 8; ++r) h[r] = fast_tanh(h[r]);
  __syncthreads();
  #pragma unroll
  for (int r = 0; r < 8; ++r) sX[wave][r][lane] = h[r];
  __syncthreads();

  float g[8];
  #pragma unroll
  for (int r = 0; r < 8; ++r) g[r] = sb2[lane];
  for (int k = 0; k < 64; ++k) {
    float w = sW2[k * 64 + lane];
    #pragma unroll
    for (int r = 0; r < 8; ++r) g[r] = fmaf(sX[wave][r][k], w, g[r]);
  }
  __syncthreads();
  #pragma unroll
  for (int r = 0; r < 8; ++r) sX[wave][r][lane] = g[r];
  __syncthreads();

  float a[8], b[8];
  #pragma unroll
  for (int r = 0; r < 8; ++r) { a[r] = 0.f; b[r] = 0.f; }
  for (int k = 0; k < 64; ++k) {
    float wa = sW12[k * 64 + lane];
    float wb = sW12[(64 + k) * 64 + lane];
    #pragma unroll
    for (int r = 0; r < 8; ++r) {
      float x = sX[wave][r][k];
      a[r] = fmaf(x, wa, a[r]);
      b[r] = fmaf(x, wb, b[r]);
    }
  }
  #pragma unroll
  for (int r = 0; r < 8; ++r) {
    int row = rowbase + r;
    if (row < N_NODES) {
      qa[row * 64 + lane] = a[r];
      qb[row * 64 + lane] = b[r];
    }
  }
}

// ---------- edge (j-sorted): 512 threads = 8 waves, 256 edges/block.
// Each wave owns 32 edges (2 row-tiles) -> every B-fragment read feeds 2 MFMAs,
// halving LDS B-bandwidth. LDS union 64KB: h2 tile / Bpack / t tile / i2 half-tile.
__global__ __launch_bounds__(512, 4) void edge_kernel(
    const int2* __restrict__ sorted_ej, const int* __restrict__ idx_i,
    const float* __restrict__ basis,
    const float* __restrict__ qa, const float* __restrict__ qb,
    const float* __restrict__ b12,
    const unsigned short* __restrict__ Bpack,
    const unsigned short* __restrict__ W2pack,
    const float* __restrict__ iib1, const float* __restrict__ iib2,
    float* __restrict__ out) {
  __shared__ __align__(16) unsigned short sB[32768];  // 64 KB
  float* sH2 = (float*)sB;
  unsigned short* sT = sB;
  float* sF = (float*)sB;

  int tid = threadIdx.x;
  int eb0 = blockIdx.x * 256;

  // ---- phase 0: gather h2 into LDS (f32, XOR-swizzled)
  for (int t = tid; t < 4096; t += 512) {
    int e = t >> 4, q = t & 15;
    int2 rec = sorted_ej[eb0 + e];
    int ii = idx_i[rec.x];
    float4 va = ((const float4*)qa)[ii * 16 + q];
    float4 vb = ((const float4*)qb)[rec.y * 16 + q];
    float4 vc = ((const float4*)b12)[q];
    float4 h;
    h.x = va.x + vb.x + vc.x;
    h.y = va.y + vb.y + vc.y;
    h.z = va.z + vb.z + vc.z;
    h.w = va.w + vb.w + vc.w;
    int dw = e * 64 + ((q * 4) ^ ((e & 7) << 3));
    *((float4*)(sH2 + dw)) = h;
  }
  __syncthreads();

  int w = tid >> 6, l = tid & 63;
  int m = l & 15, s = l >> 4;
  int el0 = w * 32 + m;          // tile0 A-row edge
  int el1 = el0 + 16;            // tile1 A-row edge (same swizzle: 16 % 8 == 0)
  int swz = (el0 & 7) << 3;

  float h2a[16], h2b[16];
  #pragma unroll
  for (int t = 0; t < 16; ++t) {
    h2a[t] = sH2[el0 * 64 + ((t * 4 + s) ^ swz)];
    h2b[t] = sH2[el1 * 64 + ((t * 4 + s) ^ swz)];
  }

  float basA[8], basB[8];
  {
    const float4* bp = (const float4*)(basis + (size_t)sorted_ej[eb0 + el0].x * 8);
    float4 b0 = bp[0], b1 = bp[1];
    basA[0] = b0.x; basA[1] = b0.y; basA[2] = b0.z; basA[3] = b0.w;
    basA[4] = b1.x; basA[5] = b1.y; basA[6] = b1.z; basA[7] = b1.w;
    const float4* bq = (const float4*)(basis + (size_t)sorted_ej[eb0 + el1].x * 8);
    float4 c0v = bq[0], c1v = bq[1];
    basB[0] = c0v.x; basB[1] = c0v.y; basB[2] = c0v.z; basB[3] = c0v.w;
    basB[4] = c1v.x; basB[5] = c1v.y; basB[6] = c1v.z; basB[7] = c1v.w;
  }
  __syncthreads();

  // ---- phase 1: stage Bpack (64 KB) into LDS
  {
    const uint4* g = (const uint4*)Bpack;
    uint4* d = (uint4*)sB;
    #pragma unroll
    for (int t = 0; t < 8; ++t) d[tid + t * 512] = g[tid + t * 512];
  }
  __syncthreads();

  // C init with ii_b1 (col = ct*16 + m), both tiles
  f32x4 c0, c1, c2, c3, g0, g1, g2, g3;
  {
    float v0 = iib1[m], v1 = iib1[16 + m], v2 = iib1[32 + m], v3 = iib1[48 + m];
    c0 = (f32x4){v0, v0, v0, v0}; g0 = c0;
    c1 = (f32x4){v1, v1, v1, v1}; g1 = c1;
    c2 = (f32x4){v2, v2, v2, v2}; g2 = c2;
    c3 = (f32x4){v3, v3, v3, v3}; g3 = c3;
  }

  // ---- main K-loop: 16 K-steps x 4 col-tiles x 2 row-tiles = 128 MFMA/wave
  const bf16x8* Bl = (const bf16x8*)sB;
  #pragma unroll
  for (int ks = 0; ks < 16; ++ks) {
    bf16x8 B0 = Bl[(ks * 4 + 0) * 64 + l];
    bf16x8 B1 = Bl[(ks * 4 + 1) * 64 + l];
    bf16x8 B2 = Bl[(ks * 4 + 2) * 64 + l];
    bf16x8 B3 = Bl[(ks * 4 + 3) * 64 + l];
    float ha = h2a[ks], hb = h2b[ks];
    union { unsigned u[4]; bf16x8 v; } A0, A1;
    #pragma unroll
    for (int j = 0; j < 4; ++j) {
      float p0 = ha * basA[2 * j];
      float p1 = ha * basA[2 * j + 1];
      asm("v_cvt_pk_bf16_f32 %0, %1, %2" : "=v"(A0.u[j]) : "v"(p0), "v"(p1));
      float q0 = hb * basB[2 * j];
      float q1 = hb * basB[2 * j + 1];
      asm("v_cvt_pk_bf16_f32 %0, %1, %2" : "=v"(A1.u[j]) : "v"(q0), "v"(q1));
    }
    c0 = __builtin_amdgcn_mfma_f32_16x16x32_bf16(A0.v, B0, c0, 0, 0, 0);
    g0 = __builtin_amdgcn_mfma_f32_16x16x32_bf16(A1.v, B0, g0, 0, 0, 0);
    c1 = __builtin_amdgcn_mfma_f32_16x16x32_bf16(A0.v, B1, c1, 0, 0, 0);
    g1 = __builtin_amdgcn_mfma_f32_16x16x32_bf16(A1.v, B1, g1, 0, 0, 0);
    c2 = __builtin_amdgcn_mfma_f32_16x16x32_bf16(A0.v, B2, c2, 0, 0, 0);
    g2 = __builtin_amdgcn_mfma_f32_16x16x32_bf16(A1.v, B2, g2, 0, 0, 0);
    c3 = __builtin_amdgcn_mfma_f32_16x16x32_bf16(A0.v, B3, c3, 0, 0, 0);
    g3 = __builtin_amdgcn_mfma_f32_16x16x32_bf16(A1.v, B3, g3, 0, 0, 0);
  }
  __syncthreads();  // all waves done reading Bpack

  // ---- phase 2: tanh -> t tile (bf16). D layout: col = ct*16+m, row(local) = s*4+r
  #pragma unroll
  for (int r = 0; r < 4; ++r) {
    int row0 = w * 32 + s * 4 + r;
    int row1 = row0 + 16;
    sT[row0 * 72 + 0 * 16 + m] = f2bf_rne(fast_tanh(c0[r]));
    sT[row0 * 72 + 1 * 16 + m] = f2bf_rne(fast_tanh(c1[r]));
    sT[row0 * 72 + 2 * 16 + m] = f2bf_rne(fast_tanh(c2[r]));
    sT[row0 * 72 + 3 * 16 + m] = f2bf_rne(fast_tanh(c3[r]));
    sT[row1 * 72 + 0 * 16 + m] = f2bf_rne(fast_tanh(g0[r]));
    sT[row1 * 72 + 1 * 16 + m] = f2bf_rne(fast_tanh(g1[r]));
    sT[row1 * 72 + 2 * 16 + m] = f2bf_rne(fast_tanh(g2[r]));
    sT[row1 * 72 + 3 * 16 + m] = f2bf_rne(fast_tanh(g3[r]));
  }
  __syncthreads();

  // ---- second GEMM: i2 = t @ ii_W2 + ii_b2 (K=64: 2 K-steps x 4 col-tiles x 2 tiles)
  f32x4 d0, d1, d2, d3, f0, f1, f2, f3;
  {
    float v0 = iib2[m], v1 = iib2[16 + m], v2 = iib2[32 + m], v3 = iib2[48 + m];
    d0 = (f32x4){v0, v0, v0, v0}; f0 = d0;
    d1 = (f32x4){v1, v1, v1, v1}; f1 = d1;
    d2 = (f32x4){v2, v2, v2, v2}; f2 = d2;
    d3 = (f32x4){v3, v3, v3, v3}; f3 = d3;
  }
  const bf16x8* Wl = (const bf16x8*)W2pack;
  #pragma unroll
  for (int ks = 0; ks < 2; ++ks) {
    bf16x8 Af0 = *(const bf16x8*)(sT + el0 * 72 + ks * 32 + s * 8);
    bf16x8 Af1 = *(const bf16x8*)(sT + el1 * 72 + ks * 32 + s * 8);
    bf16x8 W0 = Wl[(ks * 4 + 0) * 64 + l];
    bf16x8 W1 = Wl[(ks * 4 + 1) * 64 + l];
    bf16x8 W2 = Wl[(ks * 4 + 2) * 64 + l];
    bf16x8 W3 = Wl[(ks * 4 + 3) * 64 + l];
    d0 = __builtin_amdgcn_mfma_f32_16x16x32_bf16(Af0, W0, d0, 0, 0, 0);
    f0 = __builtin_amdgcn_mfma_f32_16x16x32_bf16(Af1, W0, f0, 0, 0, 0);
    d1 = __builtin_amdgcn_mfma_f32_16x16x32_bf16(Af0, W1, d1, 0, 0, 0);
    f1 = __builtin_amdgcn_mfma_f32_16x16x32_bf16(Af1, W1, f1, 0, 0, 0);
    d2 = __builtin_amdgcn_mfma_f32_16x16x32_bf16(Af0, W2, d2, 0, 0, 0);
    f2 = __builtin_amdgcn_mfma_f32_16x16x32_bf16(Af1, W2, f2, 0, 0, 0);
    d3 = __builtin_amdgcn_mfma_f32_16x16x32_bf16(Af0, W3, d3, 0, 0, 0);
    f3 = __builtin_amdgcn_mfma_f32_16x16x32_bf16(Af1, W3, f3, 0, 0, 0);
  }

  // ---- phase 3: run-aggregated scatter, two 128-edge halves through LDS (f32).
  // Wave w holds global rows w*32+{0..31}; half h hosts waves [h*4, h*4+4).
  #pragma unroll
  for (int h = 0; h < 2; ++h) {
    __syncthreads();
    if ((w >> 2) == h) {
      int lw = w & 3;
      #pragma unroll
      for (int r = 0; r < 4; ++r) {
        int row0 = lw * 32 + s * 4 + r;
        int row1 = row0 + 16;
        sF[row0 * 68 + 0  + m] = d0[r];
        sF[row0 * 68 + 16 + m] = d1[r];
        sF[row0 * 68 + 32 + m] = d2[r];
        sF[row0 * 68 + 48 + m] = d3[r];
        sF[row1 * 68 + 0  + m] = f0[r];
        sF[row1 * 68 + 16 + m] = f1[r];
        sF[row1 * 68 + 32 + m] = f2[r];
        sF[row1 * 68 + 48 + m] = f3[r];
      }
    }
    __syncthreads();
    {
      int base_e = eb0 + h * 128 + w * 16;
      float acc = sF[(w * 16) * 68 + l];
      int cur_j = sorted_ej[base_e].y;
      #pragma unroll
      for (int rr = 1; rr < 16; ++rr) {
        int nj = sorted_ej[base_e + rr].y;
        float v = sF[(w * 16 + rr) * 68 + l];
        if (nj == cur_j) {
          acc += v;
        } else {
          atomicAdd(&out[(size_t)cur_j * 64 + l], acc);
          acc = v;
          cur_j = nj;
        }
      }
      atomicAdd(&out[(size_t)cur_j * 64 + l], acc);
    }
  }
}

extern "C" void kernel_launch(void* const* d_in, const int* in_sizes, int n_in,
                              void* d_out, int out_size, void* d_ws, size_t ws_size,
                              hipStream_t stream) {
  const float* p     = (const float*)d_in[0];
  const int*   idx_i = (const int*)d_in[1];
  const int*   idx_j = (const int*)d_in[2];
  const float* basis = (const float*)d_in[3];
  const float* ppW1  = (const float*)d_in[4];
  const float* ppb1  = (const float*)d_in[5];
  const float* ppW2  = (const float*)d_in[6];
  const float* ppb2  = (const float*)d_in[7];
  const float* piW1  = (const float*)d_in[8];
  const float* pib1  = (const float*)d_in[9];
  const float* piW2  = (const float*)d_in[10];
  const float* pib2  = (const float*)d_in[11];
  const float* piW3  = (const float*)d_in[12];
  const float* iiW1  = (const float*)d_in[13];
  const float* iib1  = (const float*)d_in[14];
  const float* iiW2  = (const float*)d_in[15];
  const float* iib2  = (const float*)d_in[16];

  float* ws  = (float*)d_ws;
  float* qa  = ws;                         // 3,200,000 f
  float* qb  = ws + 3200000;               // 3,200,000 f
  float* W12 = ws + 6400000;               // 8192 f
  float* b12 = ws + 6408192;               // 64 f
  unsigned short* Bpack  = (unsigned short*)(ws + 6408256);   // 32768 bf16
  unsigned short* W2pack = (unsigned short*)(ws + 6424640);   // 4096 bf16
  int* counts    = (int*)(ws + 6426688);   // NPAD ints
  int* cursors   = (int*)(ws + 6476864);   // NPAD ints
  int2* sorted_ej = (int2*)(ws + 6527040); // 800000 int2 (end ~32.5 MB)

  hipMemsetAsync(d_out, 0, (size_t)out_size * sizeof(float), stream);
  hipMemsetAsync(counts, 0, (size_t)NPAD * sizeof(int), stream);
  hist_prep_kernel<<<3302, 256, 0, stream>>>(idx_j, piW1, pib1, piW2, pib2,
                                             piW3, iiW1, iiW2,
                                             counts, W12, b12, Bpack, W2pack);
  scan_kernel<<<49, 1024, 0, stream>>>(counts, cursors);
  sort_scatter_kernel<<<3125, 256, 0, stream>>>(idx_j, cursors, sorted_ej);
  node_kernel<<<1563, 256, 0, stream>>>(p, ppW1, ppb1, ppW2, ppb2, W12, qa, qb);
  edge_kernel<<<3125, 512, 0, stream>>>(sorted_ej, idx_i, basis,
                                        qa, qb, b12, Bpack, W2pack,
                                        iib1, iib2, (float*)d_out);
}

// Round 7
// 300.583 us; speedup vs baseline: 1.1250x; 1.1250x over previous
//
#include <hip/hip_runtime.h>

#define N_NODES 50000
#define N_EDGES 800000
#define NPAD 50176   // 49 * 1024, padded histogram size

typedef float f32x4 __attribute__((ext_vector_type(4)));
typedef short bf16x8 __attribute__((ext_vector_type(8)));

__device__ __forceinline__ float fast_tanh(float x) {
  // tanh(x) = 1 - 2/(exp(2x)+1); v_rcp_f32 (1 ulp) instead of IEEE div sequence
  float e = __expf(2.0f * x);
  float r;
  asm("v_rcp_f32 %0, %1" : "=v"(r) : "v"(e + 1.0f));
  return fmaf(-2.0f, r, 1.0f);
}

__device__ __forceinline__ unsigned short f2bf_rne(float x) {
  unsigned u = __float_as_uint(x);
  unsigned r = u + 0x7FFFu + ((u >> 16) & 1u);
  return (unsigned short)(r >> 16);
}

// 8-row GEMM micro-tile: acc[r] += sum_k X[r][k] * W[k][lane], X rows in LDS (stride 64)
__device__ __forceinline__ void gemm8(const float* __restrict__ sXrow,
                                      const float* __restrict__ sW,
                                      int lane, float acc[8]) {
  for (int k = 0; k < 64; k += 4) {
    float w0 = sW[k * 64 + lane];
    float w1 = sW[(k + 1) * 64 + lane];
    float w2 = sW[(k + 2) * 64 + lane];
    float w3 = sW[(k + 3) * 64 + lane];
    #pragma unroll
    for (int r = 0; r < 8; ++r) {
      float4 x = *(const float4*)(sXrow + r * 64 + k);
      acc[r] = fmaf(x.x, w0, fmaf(x.y, w1, fmaf(x.z, w2, fmaf(x.w, w3, acc[r]))));
    }
  }
}

// ---------- fused front: blocks [0,1563) node ; [1563,1708) prep ; [1708,4833) hist
// node: p1 = tanh(p@ppW1+b1)@ppW2+b2 ; t1 = p1@piW1[0:64] ; t2 = p1@piW1[64:128] ;
//       qa = t1@piW2 ; qb = t2@piW2      (no W12 intermediate -> no cross-dispatch dep)
// prep: Bpack (MFMA-packed bf16 of W3i = (piW3 basis-major) @ iiW1), b12, W2pack
// hist: counts[idx_j]++
__global__ __launch_bounds__(256) void front_kernel(
    const float* __restrict__ p, const int* __restrict__ idx_j,
    const float* __restrict__ ppW1, const float* __restrict__ ppb1,
    const float* __restrict__ ppW2, const float* __restrict__ ppb2,
    const float* __restrict__ piW1, const float* __restrict__ pib1,
    const float* __restrict__ piW2, const float* __restrict__ pib2,
    const float* __restrict__ piW3, const float* __restrict__ iiW1,
    const float* __restrict__ iiW2,
    int* __restrict__ counts,
    float* __restrict__ qa, float* __restrict__ qb, float* __restrict__ b12,
    unsigned short* __restrict__ Bpack, unsigned short* __restrict__ W2pack) {
  int bid = blockIdx.x;
  int tid = threadIdx.x;

  if (bid >= 1708) {  // ---------------- hist
    int e = (bid - 1708) * 256 + tid;
    if (e < N_EDGES) atomicAdd(&counts[idx_j[e]], 1);
    return;
  }
  if (bid >= 1563) {  // ---------------- prep
    int gid = (bid - 1563) * 256 + tid;
    if (gid < 32768) {
      int j = gid & 7;
      int lane = (gid >> 3) & 63;
      int ct = (gid >> 9) & 3;
      int ks = gid >> 11;
      int kidx = ks * 32 + ((lane >> 4) << 3) + j;
      int col = ct * 16 + (lane & 15);
      int k = kidx >> 3, b = kidx & 7;
      float acc = 0.f;
      #pragma unroll 8
      for (int mm = 0; mm < 64; ++mm)
        acc = fmaf(piW3[k * 512 + mm * 8 + b], iiW1[mm * 64 + col], acc);
      Bpack[gid] = f2bf_rne(acc);
    } else if (gid < 32832) {
      int c = gid - 32768;
      float acc = pib2[c];
      for (int k = 0; k < 64; ++k) acc = fmaf(pib1[k], piW2[k * 64 + c], acc);
      b12[c] = acc;
    } else if (gid < 36928) {
      int g2 = gid - 32832;
      int j = g2 & 7;
      int lane = (g2 >> 3) & 63;
      int ct = (g2 >> 9) & 3;
      int ks = g2 >> 11;
      int kidx = ks * 32 + ((lane >> 4) << 3) + j;
      int col = ct * 16 + (lane & 15);
      W2pack[g2] = f2bf_rne(iiW2[kidx * 64 + col]);
    }
    return;
  }

  // ---------------- node
  __shared__ float sW[64 * 64];
  __shared__ float sX[4][8][64];
  __shared__ float sY[4][8][64];
  int wave = tid >> 6, lane = tid & 63;
  int rowbase = bid * 32 + wave * 8;

  // stage 8 rows of p into this wave's sX slab
  float4* sXf4 = (float4*)&sX[wave][0][0];
  for (int t = lane; t < 128; t += 64) {
    int r = t >> 4, c4 = t & 15;
    int row = rowbase + r;
    float4 v = make_float4(0.f, 0.f, 0.f, 0.f);
    if (row < N_NODES) v = ((const float4*)p)[row * 16 + c4];
    sXf4[t] = v;
  }
  // phase A: h = tanh(p@ppW1 + b1)
  for (int i = tid; i < 4096; i += 256) sW[i] = ppW1[i];
  __syncthreads();
  float h[8];
  {
    float bv = ppb1[lane];
    #pragma unroll
    for (int r = 0; r < 8; ++r) h[r] = bv;
  }
  gemm8(&sX[wave][0][0], sW, lane, h);
  #pragma unroll
  for (int r = 0; r < 8; ++r) sY[wave][r][lane] = fast_tanh(h[r]);
  __syncthreads();
  // phase B: p1 = h@ppW2 + b2  -> sX
  for (int i = tid; i < 4096; i += 256) sW[i] = ppW2[i];
  __syncthreads();
  float g[8];
  {
    float bv = ppb2[lane];
    #pragma unroll
    for (int r = 0; r < 8; ++r) g[r] = bv;
  }
  gemm8(&sY[wave][0][0], sW, lane, g);
  #pragma unroll
  for (int r = 0; r < 8; ++r) sX[wave][r][lane] = g[r];
  __syncthreads();
  // phase C: t1 = p1@piW1[0:64]  -> sY
  for (int i = tid; i < 4096; i += 256) sW[i] = piW1[i];
  __syncthreads();
  float t1[8] = {0, 0, 0, 0, 0, 0, 0, 0};
  gemm8(&sX[wave][0][0], sW, lane, t1);
  #pragma unroll
  for (int r = 0; r < 8; ++r) sY[wave][r][lane] = t1[r];
  __syncthreads();
  // phase D: t2 = p1@piW1[64:128] -> sX (p1 dead after this phase's reads)
  for (int i = tid; i < 4096; i += 256) sW[i] = piW1[4096 + i];
  __syncthreads();
  float t2[8] = {0, 0, 0, 0, 0, 0, 0, 0};
  gemm8(&sX[wave][0][0], sW, lane, t2);
  __syncthreads();
  #pragma unroll
  for (int r = 0; r < 8; ++r) sX[wave][r][lane] = t2[r];
  __syncthreads();
  // phase E: qa = t1@piW2 ; qb = t2@piW2 (one weight read feeds both)
  for (int i = tid; i < 4096; i += 256) sW[i] = piW2[i];
  __syncthreads();
  float a[8] = {0, 0, 0, 0, 0, 0, 0, 0};
  float b[8] = {0, 0, 0, 0, 0, 0, 0, 0};
  for (int k = 0; k < 64; k += 4) {
    float w0 = sW[k * 64 + lane];
    float w1 = sW[(k + 1) * 64 + lane];
    float w2 = sW[(k + 2) * 64 + lane];
    float w3 = sW[(k + 3) * 64 + lane];
    #pragma unroll
    for (int r = 0; r < 8; ++r) {
      float4 x = *(const float4*)(&sY[wave][r][k]);
      float4 y = *(const float4*)(&sX[wave][r][k]);
      a[r] = fmaf(x.x, w0, fmaf(x.y, w1, fmaf(x.z, w2, fmaf(x.w, w3, a[r]))));
      b[r] = fmaf(y.x, w0, fmaf(y.y, w1, fmaf(y.z, w2, fmaf(y.w, w3, b[r]))));
    }
  }
  #pragma unroll
  for (int r = 0; r < 8; ++r) {
    int row = rowbase + r;
    if (row < N_NODES) {
      qa[row * 64 + lane] = a[r];
      qb[row * 64 + lane] = b[r];
    }
  }
}

// ---------- single-dispatch exclusive scan: block b scans chunk b; base = redundant
// grid-sum of preceding counts.
__global__ __launch_bounds__(1024) void scan_kernel(
    const int* __restrict__ counts, int* __restrict__ cursors) {
  __shared__ int buf[1024];
  __shared__ int red[16];
  int b = blockIdx.x, tid = threadIdx.x;
  int idx = b * 1024 + tid;
  int v = counts[idx];
  buf[tid] = v;
  int partial = 0;
  for (int i = tid; i < b * 1024; i += 1024) partial += counts[i];
  #pragma unroll
  for (int off = 32; off >= 1; off >>= 1) partial += __shfl_down(partial, off, 64);
  if ((tid & 63) == 0) red[tid >> 6] = partial;
  __syncthreads();
  for (int off = 1; off < 1024; off <<= 1) {
    int t = (tid >= off) ? buf[tid - off] : 0;
    __syncthreads();
    buf[tid] += t;
    __syncthreads();
  }
  int base = 0;
  #pragma unroll
  for (int i = 0; i < 16; ++i) base += red[i];
  cursors[idx] = base + buf[tid] - v;
}

// ---------- scatter edges into j-sorted order: record (idx_i, j) + orig edge id
__global__ __launch_bounds__(256) void sort_scatter_kernel(
    const int* __restrict__ idx_i, const int* __restrict__ idx_j,
    int* __restrict__ cursors,
    int2* __restrict__ sorted_ij, int* __restrict__ sorted_e) {
  int e = blockIdx.x * 256 + threadIdx.x;
  if (e < N_EDGES) {
    int j = idx_j[e];
    int pos = atomicAdd(&cursors[j], 1);
    sorted_ij[pos] = make_int2(idx_i[e], j);
    sorted_e[pos] = e;
  }
}

// ---------- edge (j-sorted): 1024 threads = 16 waves, 256 edges/block (round-5 proven).
// h2 = qa[i]+qb[j]+b12 ; s = (h2 (x) basis)@W3i + ii_b1 (MFMA, rne-bf16 A) ;
// t = tanh(s) ; i2 = t@ii_W2 + ii_b2 (MFMA) ; run-aggregated atomic scatter.
__global__ __launch_bounds__(1024, 8) void edge_kernel(
    const int2* __restrict__ sorted_ij, const int* __restrict__ sorted_e,
    const float* __restrict__ basis,
    const float* __restrict__ qa, const float* __restrict__ qb,
    const float* __restrict__ b12,
    const unsigned short* __restrict__ Bpack,
    const unsigned short* __restrict__ W2pack,
    const float* __restrict__ iib1, const float* __restrict__ iib2,
    float* __restrict__ out) {
  __shared__ __align__(16) unsigned short sB[32768];  // 64 KB
  float* sH2 = (float*)sB;
  unsigned short* sT = sB;
  float* sF = (float*)sB;

  int tid = threadIdx.x;
  int e0 = blockIdx.x * 256;

  // ---- phase 0: gather h2 into LDS (f32, XOR-swizzled). qb rows L1-hot (sorted j).
  for (int t = tid; t < 4096; t += 1024) {
    int e = t >> 4, q = t & 15;
    int2 se = sorted_ij[e0 + e];
    float4 va = ((const float4*)qa)[se.x * 16 + q];
    float4 vb = ((const float4*)qb)[se.y * 16 + q];
    float4 vc = ((const float4*)b12)[q];
    float4 h;
    h.x = va.x + vb.x + vc.x;
    h.y = va.y + vb.y + vc.y;
    h.z = va.z + vb.z + vc.z;
    h.w = va.w + vb.w + vc.w;
    int dw = e * 64 + ((q * 4) ^ ((e & 7) << 3));  // XOR keeps 16B alignment
    *((float4*)(sH2 + dw)) = h;
  }
  __syncthreads();

  int w = tid >> 6, l = tid & 63;
  int m = l & 15, s = l >> 4;
  int eloc = w * 16 + m;        // this lane's edge row (A-operand row = l&15)
  int swz = (eloc & 7) << 3;

  float h2r[16];
  #pragma unroll
  for (int t = 0; t < 16; ++t) h2r[t] = sH2[eloc * 64 + ((t * 4 + s) ^ swz)];

  float bas[8];
  {
    int eorig = sorted_e[e0 + eloc];
    const float4* bp = (const float4*)(basis + (size_t)eorig * 8);
    float4 b0 = bp[0], b1 = bp[1];
    bas[0] = b0.x; bas[1] = b0.y; bas[2] = b0.z; bas[3] = b0.w;
    bas[4] = b1.x; bas[5] = b1.y; bas[6] = b1.z; bas[7] = b1.w;
  }
  __syncthreads();

  // ---- phase 1: stage Bpack (64 KB) into LDS
  {
    const uint4* g = (const uint4*)Bpack;
    uint4* d = (uint4*)sB;
    #pragma unroll
    for (int t = 0; t < 4; ++t) d[tid + t * 1024] = g[tid + t * 1024];
  }
  __syncthreads();

  f32x4 c0, c1, c2, c3;
  {
    float v0 = iib1[m], v1 = iib1[16 + m], v2 = iib1[32 + m], v3 = iib1[48 + m];
    c0 = (f32x4){v0, v0, v0, v0};
    c1 = (f32x4){v1, v1, v1, v1};
    c2 = (f32x4){v2, v2, v2, v2};
    c3 = (f32x4){v3, v3, v3, v3};
  }

  // ---- main K-loop: 16 K-steps x 4 col-tiles, rne-bf16 A = 64 MFMA/wave
  const bf16x8* Bl = (const bf16x8*)sB;
  #pragma unroll
  for (int ks = 0; ks < 16; ++ks) {
    bf16x8 B0 = Bl[(ks * 4 + 0) * 64 + l];
    bf16x8 B1 = Bl[(ks * 4 + 1) * 64 + l];
    bf16x8 B2 = Bl[(ks * 4 + 2) * 64 + l];
    bf16x8 B3 = Bl[(ks * 4 + 3) * 64 + l];
    float hv = h2r[ks];
    union { unsigned u[4]; bf16x8 v; } A;
    #pragma unroll
    for (int j = 0; j < 4; ++j) {
      float p0 = hv * bas[2 * j];
      float p1 = hv * bas[2 * j + 1];
      asm("v_cvt_pk_bf16_f32 %0, %1, %2" : "=v"(A.u[j]) : "v"(p0), "v"(p1));
    }
    c0 = __builtin_amdgcn_mfma_f32_16x16x32_bf16(A.v, B0, c0, 0, 0, 0);
    c1 = __builtin_amdgcn_mfma_f32_16x16x32_bf16(A.v, B1, c1, 0, 0, 0);
    c2 = __builtin_amdgcn_mfma_f32_16x16x32_bf16(A.v, B2, c2, 0, 0, 0);
    c3 = __builtin_amdgcn_mfma_f32_16x16x32_bf16(A.v, B3, c3, 0, 0, 0);
  }
  __syncthreads();  // all waves done reading Bpack

  // ---- phase 2: tanh -> t tile (bf16). D layout: col = ct*16+m, row(local) = s*4+r
  #pragma unroll
  for (int r = 0; r < 4; ++r) {
    int row = w * 16 + s * 4 + r;
    sT[row * 72 + 0 * 16 + m] = f2bf_rne(fast_tanh(c0[r]));
    sT[row * 72 + 1 * 16 + m] = f2bf_rne(fast_tanh(c1[r]));
    sT[row * 72 + 2 * 16 + m] = f2bf_rne(fast_tanh(c2[r]));
    sT[row * 72 + 3 * 16 + m] = f2bf_rne(fast_tanh(c3[r]));
  }
  __syncthreads();

  // ---- second GEMM: i2 = t @ ii_W2 + ii_b2 (K=64: 2 K-steps x 4 col-tiles)
  f32x4 d0, d1, d2, d3;
  {
    float v0 = iib2[m], v1 = iib2[16 + m], v2 = iib2[32 + m], v3 = iib2[48 + m];
    d0 = (f32x4){v0, v0, v0, v0};
    d1 = (f32x4){v1, v1, v1, v1};
    d2 = (f32x4){v2, v2, v2, v2};
    d3 = (f32x4){v3, v3, v3, v3};
  }
  const bf16x8* Wl = (const bf16x8*)W2pack;
  #pragma unroll
  for (int ks = 0; ks < 2; ++ks) {
    bf16x8 Af = *(const bf16x8*)(sT + eloc * 72 + ks * 32 + s * 8);
    d0 = __builtin_amdgcn_mfma_f32_16x16x32_bf16(Af, Wl[(ks * 4 + 0) * 64 + l], d0, 0, 0, 0);
    d1 = __builtin_amdgcn_mfma_f32_16x16x32_bf16(Af, Wl[(ks * 4 + 1) * 64 + l], d1, 0, 0, 0);
    d2 = __builtin_amdgcn_mfma_f32_16x16x32_bf16(Af, Wl[(ks * 4 + 2) * 64 + l], d2, 0, 0, 0);
    d3 = __builtin_amdgcn_mfma_f32_16x16x32_bf16(Af, Wl[(ks * 4 + 3) * 64 + l], d3, 0, 0, 0);
  }

  // ---- phase 3: run-aggregated scatter (two 128-edge halves through LDS)
  #pragma unroll
  for (int h = 0; h < 2; ++h) {
    __syncthreads();
    if ((w >> 3) == h) {
      int wl = w & 7;
      #pragma unroll
      for (int r = 0; r < 4; ++r) {
        int row = wl * 16 + s * 4 + r;
        sF[row * 68 + 0  + m] = d0[r];
        sF[row * 68 + 16 + m] = d1[r];
        sF[row * 68 + 32 + m] = d2[r];
        sF[row * 68 + 48 + m] = d3[r];
      }
    }
    __syncthreads();
    {
      int base_e = e0 + h * 128 + w * 8;
      float acc = sF[(w * 8) * 68 + l];
      int cur_j = sorted_ij[base_e].y;
      #pragma unroll
      for (int rr = 1; rr < 8; ++rr) {
        int nj = sorted_ij[base_e + rr].y;
        float v = sF[(w * 8 + rr) * 68 + l];
        if (nj == cur_j) {
          acc += v;
        } else {
          atomicAdd(&out[(size_t)cur_j * 64 + l], acc);
          acc = v;
          cur_j = nj;
        }
      }
      atomicAdd(&out[(size_t)cur_j * 64 + l], acc);
    }
  }
}

extern "C" void kernel_launch(void* const* d_in, const int* in_sizes, int n_in,
                              void* d_out, int out_size, void* d_ws, size_t ws_size,
                              hipStream_t stream) {
  const float* p     = (const float*)d_in[0];
  const int*   idx_i = (const int*)d_in[1];
  const int*   idx_j = (const int*)d_in[2];
  const float* basis = (const float*)d_in[3];
  const float* ppW1  = (const float*)d_in[4];
  const float* ppb1  = (const float*)d_in[5];
  const float* ppW2  = (const float*)d_in[6];
  const float* ppb2  = (const float*)d_in[7];
  const float* piW1  = (const float*)d_in[8];
  const float* pib1  = (const float*)d_in[9];
  const float* piW2  = (const float*)d_in[10];
  const float* pib2  = (const float*)d_in[11];
  const float* piW3  = (const float*)d_in[12];
  const float* iiW1  = (const float*)d_in[13];
  const float* iib1  = (const float*)d_in[14];
  const float* iiW2  = (const float*)d_in[15];
  const float* iib2  = (const float*)d_in[16];

  float* ws  = (float*)d_ws;
  float* qa  = ws;                          // 3,200,000 f
  float* qb  = ws + 3200000;                // 3,200,000 f
  float* b12 = ws + 6400000;                // 64 f
  unsigned short* Bpack  = (unsigned short*)(ws + 6400064);   // 32768 bf16 (16384 f)
  unsigned short* W2pack = (unsigned short*)(ws + 6416448);   // 4096 bf16 (2048 f)
  int* counts    = (int*)(ws + 6418496);    // NPAD ints
  int* cursors   = (int*)(ws + 6468672);    // NPAD ints
  int2* sorted_ij = (int2*)(ws + 6518848);  // 800000 int2 (8B-aligned)
  int* sorted_e   = (int*)(ws + 8118848);   // 800000 ints (end ~35.7 MB)

  hipMemsetAsync(d_out, 0, (size_t)out_size * sizeof(float), stream);
  hipMemsetAsync(counts, 0, (size_t)NPAD * sizeof(int), stream);
  front_kernel<<<4833, 256, 0, stream>>>(p, idx_j, ppW1, ppb1, ppW2, ppb2,
                                         piW1, pib1, piW2, pib2, piW3, iiW1, iiW2,
                                         counts, qa, qb, b12, Bpack, W2pack);
  scan_kernel<<<49, 1024, 0, stream>>>(counts, cursors);
  sort_scatter_kernel<<<3125, 256, 0, stream>>>(idx_i, idx_j, cursors,
                                                sorted_ij, sorted_e);
  edge_kernel<<<3125, 1024, 0, stream>>>(sorted_ij, sorted_e, basis,
                                         qa, qb, b12, Bpack, W2pack,
                                         iib1, iib2, (float*)d_out);
}

// Round 8
// 251.951 us; speedup vs baseline: 1.3421x; 1.1930x over previous
//
#include <hip/hip_runtime.h>

#define N_NODES 50000
#define N_EDGES 800000
#define NPAD 50176   // 49 * 1024, padded histogram size

typedef float f32x4 __attribute__((ext_vector_type(4)));
typedef short bf16x8 __attribute__((ext_vector_type(8)));

__device__ __forceinline__ float fast_tanh(float x) {
  // tanh(x) = 1 - 2/(exp(2x)+1); v_rcp_f32 (1 ulp) instead of IEEE div sequence
  float e = __expf(2.0f * x);
  float r;
  asm("v_rcp_f32 %0, %1" : "=v"(r) : "v"(e + 1.0f));
  return fmaf(-2.0f, r, 1.0f);
}

__device__ __forceinline__ unsigned short f2bf_rne(float x) {
  unsigned u = __float_as_uint(x);
  unsigned r = u + 0x7FFFu + ((u >> 16) & 1u);
  return (unsigned short)(r >> 16);
}

// ---- pack a 64x64 f32 weight (row-major W[k][col]) into MFMA B-fragment order, bf16:
// dst[((ks*4+ct)*64 + lane)*8 + j] = bf16( W[ks*32 + (lane>>4)*8 + j][ct*16 + (lane&15)] )
// one thread packs one 8-entry fragment slot (tid in [0,512)).
__device__ __forceinline__ void packW(const float* __restrict__ W,
                                      unsigned short* __restrict__ dst, int tid) {
  int ks = tid >> 8, ct = (tid >> 6) & 3, lane = tid & 63;
  int k0 = ks * 32 + ((lane >> 4) << 3);
  int col = ct * 16 + (lane & 15);
  const float* src = W + k0 * 64 + col;
  unsigned u[4];
  #pragma unroll
  for (int jj = 0; jj < 4; ++jj) {
    float v0 = src[(2 * jj) * 64];
    float v1 = src[(2 * jj + 1) * 64];
    asm("v_cvt_pk_bf16_f32 %0, %1, %2" : "=v"(u[jj]) : "v"(v0), "v"(v1));
  }
  *(uint4*)(dst + (size_t)tid * 8) = make_uint4(u[0], u[1], u[2], u[3]);
}

// ---- one 128x64x64 GEMM step on MFMA: acc[ct] += ActIn(16 rows of wave w) @ Bpk
// ActIn: bf16 [128][64], col XOR-swizzled by ((row&7)<<3).
__device__ __forceinline__ void mfma_gemm(const unsigned short* __restrict__ actIn,
                                          const unsigned short* __restrict__ bpk,
                                          int w, int l, f32x4 acc[4]) {
  int m = l & 15, s = l >> 4;
  int row = w * 16 + m;
  int sw = (m & 7) << 3;  // row&7 == m&7 (w*16 multiple of 8)
  #pragma unroll
  for (int ks = 0; ks < 2; ++ks) {
    bf16x8 a = *(const bf16x8*)(actIn + row * 64 + ((ks * 32 + s * 8) ^ sw));
    #pragma unroll
    for (int ct = 0; ct < 4; ++ct) {
      bf16x8 b = *(const bf16x8*)(bpk + ((size_t)((ks * 4 + ct) * 64 + l)) * 8);
      acc[ct] = __builtin_amdgcn_mfma_f32_16x16x32_bf16(a, b, acc[ct], 0, 0, 0);
    }
  }
}

// ---- write MFMA C (col=ct*16+m, row=s*4+r) to a bf16 act tile (swizzled), opt tanh
__device__ __forceinline__ void store_act(unsigned short* __restrict__ actOut,
                                          int w, int l, const f32x4 acc[4],
                                          bool do_tanh) {
  int m = l & 15, s = l >> 4;
  #pragma unroll
  for (int ct = 0; ct < 4; ++ct) {
    #pragma unroll
    for (int r = 0; r < 4; ++r) {
      int row = w * 16 + s * 4 + r;
      float v = acc[ct][r];
      if (do_tanh) v = fast_tanh(v);
      actOut[row * 64 + ((ct * 16 + m) ^ ((row & 7) << 3))] = f2bf_rne(v);
    }
  }
}

// ---------- fused front, 512 threads/block:
// blocks [0,391):   node MLP on MFMA (128 nodes/block) -> qa, qb
// blocks [391,464): prep (Bpack / b12 / W2pack)
// blocks [464,2027): histogram of idx_j
__global__ __launch_bounds__(512) void front_kernel(
    const float* __restrict__ p, const int* __restrict__ idx_j,
    const float* __restrict__ ppW1, const float* __restrict__ ppb1,
    const float* __restrict__ ppW2, const float* __restrict__ ppb2,
    const float* __restrict__ piW1, const float* __restrict__ pib1,
    const float* __restrict__ piW2, const float* __restrict__ pib2,
    const float* __restrict__ piW3, const float* __restrict__ iiW1,
    const float* __restrict__ iiW2,
    int* __restrict__ counts,
    float* __restrict__ qa, float* __restrict__ qb, float* __restrict__ b12,
    unsigned short* __restrict__ Bpack, unsigned short* __restrict__ W2pack) {
  int bid = blockIdx.x;
  int tid = threadIdx.x;

  if (bid >= 464) {  // ---------------- hist
    int e = (bid - 464) * 512 + tid;
    if (e < N_EDGES) atomicAdd(&counts[idx_j[e]], 1);
    return;
  }
  if (bid >= 391) {  // ---------------- prep
    int gid = (bid - 391) * 512 + tid;
    if (gid < 32768) {
      int j = gid & 7;
      int lane = (gid >> 3) & 63;
      int ct = (gid >> 9) & 3;
      int ks = gid >> 11;
      int kidx = ks * 32 + ((lane >> 4) << 3) + j;
      int col = ct * 16 + (lane & 15);
      int k = kidx >> 3, b = kidx & 7;
      float acc = 0.f;
      #pragma unroll 8
      for (int mm = 0; mm < 64; ++mm)
        acc = fmaf(piW3[k * 512 + mm * 8 + b], iiW1[mm * 64 + col], acc);
      Bpack[gid] = f2bf_rne(acc);
    } else if (gid < 32832) {
      int c = gid - 32768;
      float acc = pib2[c];
      for (int k = 0; k < 64; ++k) acc = fmaf(pib1[k], piW2[k * 64 + c], acc);
      b12[c] = acc;
    } else if (gid < 36928) {
      int g2 = gid - 32832;
      int j = g2 & 7;
      int lane = (g2 >> 3) & 63;
      int ct = (g2 >> 9) & 3;
      int ks = g2 >> 11;
      int kidx = ks * 32 + ((lane >> 4) << 3) + j;
      int col = ct * 16 + (lane & 15);
      W2pack[g2] = f2bf_rne(iiW2[kidx * 64 + col]);
    }
    return;
  }

  // ---------------- node (MFMA): X -> tanh(X@W1+b1) -> @W2+b2 = p1 ;
  // t1 = p1@piW1a ; qa = t1@piW2 ; t2 = p1@piW1b ; qb = t2@piW2
  __shared__ __align__(16) unsigned short sBpk[2][4096];  // 16 KB, 2 weight slots
  __shared__ __align__(16) unsigned short sAct[2][8192];  // 32 KB, 2 act buffers

  int w = tid >> 6, l = tid & 63;
  int m = l & 15;
  int nb0 = bid * 128;

  // stage X = p tile -> bf16 swizzled sAct[0]
  for (int t = tid; t < 2048; t += 512) {
    int row = t >> 4, q = t & 15;
    int g = nb0 + row;
    float4 v = make_float4(0.f, 0.f, 0.f, 0.f);
    if (g < N_NODES) v = ((const float4*)p)[g * 16 + q];
    unsigned u0, u1;
    asm("v_cvt_pk_bf16_f32 %0, %1, %2" : "=v"(u0) : "v"(v.x), "v"(v.y));
    asm("v_cvt_pk_bf16_f32 %0, %1, %2" : "=v"(u1) : "v"(v.z), "v"(v.w));
    int sw = (row & 7) << 3;
    *(uint2*)(&sAct[0][row * 64 + ((q * 4) ^ sw)]) = make_uint2(u0, u1);
  }
  packW(ppW1, sBpk[0], tid);
  packW(ppW2, sBpk[1], tid);
  __syncthreads();

  f32x4 acc[4];
  // phase A: h = tanh(X@ppW1 + b1) -> sAct[1]
  #pragma unroll
  for (int ct = 0; ct < 4; ++ct) {
    float bv = ppb1[ct * 16 + m];
    acc[ct] = (f32x4){bv, bv, bv, bv};
  }
  mfma_gemm(sAct[0], sBpk[0], w, l, acc);
  store_act(sAct[1], w, l, acc, true);
  __syncthreads();

  // phase B: p1 = h@ppW2 + b2 -> sAct[0]
  #pragma unroll
  for (int ct = 0; ct < 4; ++ct) {
    float bv = ppb2[ct * 16 + m];
    acc[ct] = (f32x4){bv, bv, bv, bv};
  }
  mfma_gemm(sAct[1], sBpk[1], w, l, acc);
  store_act(sAct[0], w, l, acc, false);
  __syncthreads();

  // repack weights: slot0 = piW1a, slot1 = piW2
  packW(piW1, sBpk[0], tid);
  packW(piW2, sBpk[1], tid);
  __syncthreads();

  // phase C: t1 = p1@piW1a -> sAct[1]
  #pragma unroll
  for (int ct = 0; ct < 4; ++ct) acc[ct] = (f32x4){0.f, 0.f, 0.f, 0.f};
  mfma_gemm(sAct[0], sBpk[0], w, l, acc);
  store_act(sAct[1], w, l, acc, false);
  __syncthreads();

  // phase E: qa = t1@piW2 -> global ; and repack slot0 = piW1b
  #pragma unroll
  for (int ct = 0; ct < 4; ++ct) acc[ct] = (f32x4){0.f, 0.f, 0.f, 0.f};
  mfma_gemm(sAct[1], sBpk[1], w, l, acc);
  {
    int s = l >> 4;
    #pragma unroll
    for (int ct = 0; ct < 4; ++ct)
      #pragma unroll
      for (int r = 0; r < 4; ++r) {
        int rg = nb0 + w * 16 + s * 4 + r;
        if (rg < N_NODES) qa[(size_t)rg * 64 + ct * 16 + m] = acc[ct][r];
      }
  }
  packW(piW1 + 4096, sBpk[0], tid);
  __syncthreads();

  // phase D: t2 = p1@piW1b -> sAct[1]
  #pragma unroll
  for (int ct = 0; ct < 4; ++ct) acc[ct] = (f32x4){0.f, 0.f, 0.f, 0.f};
  mfma_gemm(sAct[0], sBpk[0], w, l, acc);
  store_act(sAct[1], w, l, acc, false);
  __syncthreads();

  // phase F: qb = t2@piW2 -> global
  #pragma unroll
  for (int ct = 0; ct < 4; ++ct) acc[ct] = (f32x4){0.f, 0.f, 0.f, 0.f};
  mfma_gemm(sAct[1], sBpk[1], w, l, acc);
  {
    int s = l >> 4;
    #pragma unroll
    for (int ct = 0; ct < 4; ++ct)
      #pragma unroll
      for (int r = 0; r < 4; ++r) {
        int rg = nb0 + w * 16 + s * 4 + r;
        if (rg < N_NODES) qb[(size_t)rg * 64 + ct * 16 + m] = acc[ct][r];
      }
  }
}

// ---------- single-dispatch exclusive scan: block b scans chunk b; base = redundant
// grid-sum of preceding counts.
__global__ __launch_bounds__(1024) void scan_kernel(
    const int* __restrict__ counts, int* __restrict__ cursors) {
  __shared__ int buf[1024];
  __shared__ int red[16];
  int b = blockIdx.x, tid = threadIdx.x;
  int idx = b * 1024 + tid;
  int v = counts[idx];
  buf[tid] = v;
  int partial = 0;
  for (int i = tid; i < b * 1024; i += 1024) partial += counts[i];
  #pragma unroll
  for (int off = 32; off >= 1; off >>= 1) partial += __shfl_down(partial, off, 64);
  if ((tid & 63) == 0) red[tid >> 6] = partial;
  __syncthreads();
  for (int off = 1; off < 1024; off <<= 1) {
    int t = (tid >= off) ? buf[tid - off] : 0;
    __syncthreads();
    buf[tid] += t;
    __syncthreads();
  }
  int base = 0;
  #pragma unroll
  for (int i = 0; i < 16; ++i) base += red[i];
  cursors[idx] = base + buf[tid] - v;
}

// ---------- scatter edges into j-sorted order: record (idx_i, j) + orig edge id
__global__ __launch_bounds__(256) void sort_scatter_kernel(
    const int* __restrict__ idx_i, const int* __restrict__ idx_j,
    int* __restrict__ cursors,
    int2* __restrict__ sorted_ij, int* __restrict__ sorted_e) {
  int e = blockIdx.x * 256 + threadIdx.x;
  if (e < N_EDGES) {
    int j = idx_j[e];
    int pos = atomicAdd(&cursors[j], 1);
    sorted_ij[pos] = make_int2(idx_i[e], j);
    sorted_e[pos] = e;
  }
}

// ---------- edge (j-sorted): 1024 threads = 16 waves, 256 edges/block (round-5 proven).
// h2 = qa[i]+qb[j]+b12 ; s = (h2 (x) basis)@W3i + ii_b1 (MFMA, rne-bf16 A) ;
// t = tanh(s) ; i2 = t@ii_W2 + ii_b2 (MFMA) ; run-aggregated atomic scatter.
__global__ __launch_bounds__(1024, 8) void edge_kernel(
    const int2* __restrict__ sorted_ij, const int* __restrict__ sorted_e,
    const float* __restrict__ basis,
    const float* __restrict__ qa, const float* __restrict__ qb,
    const float* __restrict__ b12,
    const unsigned short* __restrict__ Bpack,
    const unsigned short* __restrict__ W2pack,
    const float* __restrict__ iib1, const float* __restrict__ iib2,
    float* __restrict__ out) {
  __shared__ __align__(16) unsigned short sB[32768];  // 64 KB
  float* sH2 = (float*)sB;
  unsigned short* sT = sB;
  float* sF = (float*)sB;

  int tid = threadIdx.x;
  int e0 = blockIdx.x * 256;

  // ---- phase 0: gather h2 into LDS (f32, XOR-swizzled). qb rows L1-hot (sorted j).
  for (int t = tid; t < 4096; t += 1024) {
    int e = t >> 4, q = t & 15;
    int2 se = sorted_ij[e0 + e];
    float4 va = ((const float4*)qa)[se.x * 16 + q];
    float4 vb = ((const float4*)qb)[se.y * 16 + q];
    float4 vc = ((const float4*)b12)[q];
    float4 h;
    h.x = va.x + vb.x + vc.x;
    h.y = va.y + vb.y + vc.y;
    h.z = va.z + vb.z + vc.z;
    h.w = va.w + vb.w + vc.w;
    int dw = e * 64 + ((q * 4) ^ ((e & 7) << 3));  // XOR keeps 16B alignment
    *((float4*)(sH2 + dw)) = h;
  }
  __syncthreads();

  int w = tid >> 6, l = tid & 63;
  int m = l & 15, s = l >> 4;
  int eloc = w * 16 + m;        // this lane's edge row (A-operand row = l&15)
  int swz = (eloc & 7) << 3;

  float h2r[16];
  #pragma unroll
  for (int t = 0; t < 16; ++t) h2r[t] = sH2[eloc * 64 + ((t * 4 + s) ^ swz)];

  float bas[8];
  {
    int eorig = sorted_e[e0 + eloc];
    const float4* bp = (const float4*)(basis + (size_t)eorig * 8);
    float4 b0 = bp[0], b1 = bp[1];
    bas[0] = b0.x; bas[1] = b0.y; bas[2] = b0.z; bas[3] = b0.w;
    bas[4] = b1.x; bas[5] = b1.y; bas[6] = b1.z; bas[7] = b1.w;
  }
  __syncthreads();

  // ---- phase 1: stage Bpack (64 KB) into LDS
  {
    const uint4* g = (const uint4*)Bpack;
    uint4* d = (uint4*)sB;
    #pragma unroll
    for (int t = 0; t < 4; ++t) d[tid + t * 1024] = g[tid + t * 1024];
  }
  __syncthreads();

  f32x4 c0, c1, c2, c3;
  {
    float v0 = iib1[m], v1 = iib1[16 + m], v2 = iib1[32 + m], v3 = iib1[48 + m];
    c0 = (f32x4){v0, v0, v0, v0};
    c1 = (f32x4){v1, v1, v1, v1};
    c2 = (f32x4){v2, v2, v2, v2};
    c3 = (f32x4){v3, v3, v3, v3};
  }

  // ---- main K-loop: 16 K-steps x 4 col-tiles, rne-bf16 A = 64 MFMA/wave
  const bf16x8* Bl = (const bf16x8*)sB;
  #pragma unroll
  for (int ks = 0; ks < 16; ++ks) {
    bf16x8 B0 = Bl[(ks * 4 + 0) * 64 + l];
    bf16x8 B1 = Bl[(ks * 4 + 1) * 64 + l];
    bf16x8 B2 = Bl[(ks * 4 + 2) * 64 + l];
    bf16x8 B3 = Bl[(ks * 4 + 3) * 64 + l];
    float hv = h2r[ks];
    union { unsigned u[4]; bf16x8 v; } A;
    #pragma unroll
    for (int j = 0; j < 4; ++j) {
      float p0 = hv * bas[2 * j];
      float p1 = hv * bas[2 * j + 1];
      asm("v_cvt_pk_bf16_f32 %0, %1, %2" : "=v"(A.u[j]) : "v"(p0), "v"(p1));
    }
    c0 = __builtin_amdgcn_mfma_f32_16x16x32_bf16(A.v, B0, c0, 0, 0, 0);
    c1 = __builtin_amdgcn_mfma_f32_16x16x32_bf16(A.v, B1, c1, 0, 0, 0);
    c2 = __builtin_amdgcn_mfma_f32_16x16x32_bf16(A.v, B2, c2, 0, 0, 0);
    c3 = __builtin_amdgcn_mfma_f32_16x16x32_bf16(A.v, B3, c3, 0, 0, 0);
  }
  __syncthreads();  // all waves done reading Bpack

  // ---- phase 2: tanh -> t tile (bf16). D layout: col = ct*16+m, row(local) = s*4+r
  #pragma unroll
  for (int r = 0; r < 4; ++r) {
    int row = w * 16 + s * 4 + r;
    sT[row * 72 + 0 * 16 + m] = f2bf_rne(fast_tanh(c0[r]));
    sT[row * 72 + 1 * 16 + m] = f2bf_rne(fast_tanh(c1[r]));
    sT[row * 72 + 2 * 16 + m] = f2bf_rne(fast_tanh(c2[r]));
    sT[row * 72 + 3 * 16 + m] = f2bf_rne(fast_tanh(c3[r]));
  }
  __syncthreads();

  // ---- second GEMM: i2 = t @ ii_W2 + ii_b2 (K=64: 2 K-steps x 4 col-tiles)
  f32x4 d0, d1, d2, d3;
  {
    float v0 = iib2[m], v1 = iib2[16 + m], v2 = iib2[32 + m], v3 = iib2[48 + m];
    d0 = (f32x4){v0, v0, v0, v0};
    d1 = (f32x4){v1, v1, v1, v1};
    d2 = (f32x4){v2, v2, v2, v2};
    d3 = (f32x4){v3, v3, v3, v3};
  }
  const bf16x8* Wl = (const bf16x8*)W2pack;
  #pragma unroll
  for (int ks = 0; ks < 2; ++ks) {
    bf16x8 Af = *(const bf16x8*)(sT + eloc * 72 + ks * 32 + s * 8);
    d0 = __builtin_amdgcn_mfma_f32_16x16x32_bf16(Af, Wl[(ks * 4 + 0) * 64 + l], d0, 0, 0, 0);
    d1 = __builtin_amdgcn_mfma_f32_16x16x32_bf16(Af, Wl[(ks * 4 + 1) * 64 + l], d1, 0, 0, 0);
    d2 = __builtin_amdgcn_mfma_f32_16x16x32_bf16(Af, Wl[(ks * 4 + 2) * 64 + l], d2, 0, 0, 0);
    d3 = __builtin_amdgcn_mfma_f32_16x16x32_bf16(Af, Wl[(ks * 4 + 3) * 64 + l], d3, 0, 0, 0);
  }

  // ---- phase 3: run-aggregated scatter (two 128-edge halves through LDS)
  #pragma unroll
  for (int h = 0; h < 2; ++h) {
    __syncthreads();
    if ((w >> 3) == h) {
      int wl = w & 7;
      #pragma unroll
      for (int r = 0; r < 4; ++r) {
        int row = wl * 16 + s * 4 + r;
        sF[row * 68 + 0  + m] = d0[r];
        sF[row * 68 + 16 + m] = d1[r];
        sF[row * 68 + 32 + m] = d2[r];
        sF[row * 68 + 48 + m] = d3[r];
      }
    }
    __syncthreads();
    {
      int base_e = e0 + h * 128 + w * 8;
      float acc = sF[(w * 8) * 68 + l];
      int cur_j = sorted_ij[base_e].y;
      #pragma unroll
      for (int rr = 1; rr < 8; ++rr) {
        int nj = sorted_ij[base_e + rr].y;
        float v = sF[(w * 8 + rr) * 68 + l];
        if (nj == cur_j) {
          acc += v;
        } else {
          atomicAdd(&out[(size_t)cur_j * 64 + l], acc);
          acc = v;
          cur_j = nj;
        }
      }
      atomicAdd(&out[(size_t)cur_j * 64 + l], acc);
    }
  }
}

extern "C" void kernel_launch(void* const* d_in, const int* in_sizes, int n_in,
                              void* d_out, int out_size, void* d_ws, size_t ws_size,
                              hipStream_t stream) {
  const float* p     = (const float*)d_in[0];
  const int*   idx_i = (const int*)d_in[1];
  const int*   idx_j = (const int*)d_in[2];
  const float* basis = (const float*)d_in[3];
  const float* ppW1  = (const float*)d_in[4];
  const float* ppb1  = (const float*)d_in[5];
  const float* ppW2  = (const float*)d_in[6];
  const float* ppb2  = (const float*)d_in[7];
  const float* piW1  = (const float*)d_in[8];
  const float* pib1  = (const float*)d_in[9];
  const float* piW2  = (const float*)d_in[10];
  const float* pib2  = (const float*)d_in[11];
  const float* piW3  = (const float*)d_in[12];
  const float* iiW1  = (const float*)d_in[13];
  const float* iib1  = (const float*)d_in[14];
  const float* iiW2  = (const float*)d_in[15];
  const float* iib2  = (const float*)d_in[16];

  float* ws  = (float*)d_ws;
  float* qa  = ws;                          // 3,200,000 f
  float* qb  = ws + 3200000;                // 3,200,000 f
  float* b12 = ws + 6400000;                // 64 f
  unsigned short* Bpack  = (unsigned short*)(ws + 6400064);   // 32768 bf16 (16384 f)
  unsigned short* W2pack = (unsigned short*)(ws + 6416448);   // 4096 bf16 (2048 f)
  int* counts    = (int*)(ws + 6418496);    // NPAD ints
  int* cursors   = (int*)(ws + 6468672);    // NPAD ints
  int2* sorted_ij = (int2*)(ws + 6518848);  // 800000 int2 (8B-aligned)
  int* sorted_e   = (int*)(ws + 8118848);   // 800000 ints (end ~35.7 MB)

  hipMemsetAsync(d_out, 0, (size_t)out_size * sizeof(float), stream);
  hipMemsetAsync(counts, 0, (size_t)NPAD * sizeof(int), stream);
  front_kernel<<<2027, 512, 0, stream>>>(p, idx_j, ppW1, ppb1, ppW2, ppb2,
                                         piW1, pib1, piW2, pib2, piW3, iiW1, iiW2,
                                         counts, qa, qb, b12, Bpack, W2pack);
  scan_kernel<<<49, 1024, 0, stream>>>(counts, cursors);
  sort_scatter_kernel<<<3125, 256, 0, stream>>>(idx_i, idx_j, cursors,
                                                sorted_ij, sorted_e);
  edge_kernel<<<3125, 1024, 0, stream>>>(sorted_ij, sorted_e, basis,
                                         qa, qb, b12, Bpack, W2pack,
                                         iib1, iib2, (float*)d_out);
}

// Round 9
// 245.657 us; speedup vs baseline: 1.3765x; 1.0256x over previous
//
#include <hip/hip_runtime.h>

#define N_NODES 50000
#define N_EDGES 800000
#define NPAD 50176   // 49 * 1024, padded histogram size

typedef float f32x4 __attribute__((ext_vector_type(4)));
typedef short bf16x8 __attribute__((ext_vector_type(8)));

__device__ __forceinline__ float fast_tanh(float x) {
  // tanh(x) = 1 - 2/(exp(2x)+1); v_rcp_f32 (1 ulp) instead of IEEE div sequence
  float e = __expf(2.0f * x);
  float r;
  asm("v_rcp_f32 %0, %1" : "=v"(r) : "v"(e + 1.0f));
  return fmaf(-2.0f, r, 1.0f);
}

__device__ __forceinline__ unsigned short f2bf_rne(float x) {
  unsigned u = __float_as_uint(x);
  unsigned r = u + 0x7FFFu + ((u >> 16) & 1u);
  return (unsigned short)(r >> 16);
}

// ---- pack a 64x64 f32 weight (row-major W[k][col]) into MFMA B-fragment order, bf16
__device__ __forceinline__ void packW(const float* __restrict__ W,
                                      unsigned short* __restrict__ dst, int tid) {
  int ks = tid >> 8, ct = (tid >> 6) & 3, lane = tid & 63;
  int k0 = ks * 32 + ((lane >> 4) << 3);
  int col = ct * 16 + (lane & 15);
  const float* src = W + k0 * 64 + col;
  unsigned u[4];
  #pragma unroll
  for (int jj = 0; jj < 4; ++jj) {
    float v0 = src[(2 * jj) * 64];
    float v1 = src[(2 * jj + 1) * 64];
    asm("v_cvt_pk_bf16_f32 %0, %1, %2" : "=v"(u[jj]) : "v"(v0), "v"(v1));
  }
  *(uint4*)(dst + (size_t)tid * 8) = make_uint4(u[0], u[1], u[2], u[3]);
}

// ---- one 128x64x64 GEMM step on MFMA: acc[ct] += ActIn(16 rows of wave w) @ Bpk
__device__ __forceinline__ void mfma_gemm(const unsigned short* __restrict__ actIn,
                                          const unsigned short* __restrict__ bpk,
                                          int w, int l, f32x4 acc[4]) {
  int m = l & 15, s = l >> 4;
  int row = w * 16 + m;
  int sw = (m & 7) << 3;
  #pragma unroll
  for (int ks = 0; ks < 2; ++ks) {
    bf16x8 a = *(const bf16x8*)(actIn + row * 64 + ((ks * 32 + s * 8) ^ sw));
    #pragma unroll
    for (int ct = 0; ct < 4; ++ct) {
      bf16x8 b = *(const bf16x8*)(bpk + ((size_t)((ks * 4 + ct) * 64 + l)) * 8);
      acc[ct] = __builtin_amdgcn_mfma_f32_16x16x32_bf16(a, b, acc[ct], 0, 0, 0);
    }
  }
}

// ---- write MFMA C (col=ct*16+m, row=s*4+r) to a bf16 act tile (swizzled), opt tanh
__device__ __forceinline__ void store_act(unsigned short* __restrict__ actOut,
                                          int w, int l, const f32x4 acc[4],
                                          bool do_tanh) {
  int m = l & 15, s = l >> 4;
  #pragma unroll
  for (int ct = 0; ct < 4; ++ct) {
    #pragma unroll
    for (int r = 0; r < 4; ++r) {
      int row = w * 16 + s * 4 + r;
      float v = acc[ct][r];
      if (do_tanh) v = fast_tanh(v);
      actOut[row * 64 + ((ct * 16 + m) ^ ((row & 7) << 3))] = f2bf_rne(v);
    }
  }
}

// ---------- D1: hist + prep (512 threads).  blocks [0,1563): hist ; [1563,1636): prep
__global__ __launch_bounds__(512) void hist_prep_kernel(
    const int* __restrict__ idx_j,
    const float* __restrict__ piW2, const float* __restrict__ pib1,
    const float* __restrict__ pib2,
    const float* __restrict__ piW3, const float* __restrict__ iiW1,
    const float* __restrict__ iiW2,
    int* __restrict__ counts, float* __restrict__ b12,
    unsigned short* __restrict__ Bpack, unsigned short* __restrict__ W2pack) {
  int bid = blockIdx.x;
  int tid = threadIdx.x;
  if (bid < 1563) {  // hist
    int e = bid * 512 + tid;
    if (e < N_EDGES) atomicAdd(&counts[idx_j[e]], 1);
    return;
  }
  int gid = (bid - 1563) * 512 + tid;
  if (gid < 32768) {
    int j = gid & 7;
    int lane = (gid >> 3) & 63;
    int ct = (gid >> 9) & 3;
    int ks = gid >> 11;
    int kidx = ks * 32 + ((lane >> 4) << 3) + j;
    int col = ct * 16 + (lane & 15);
    int k = kidx >> 3, b = kidx & 7;
    float acc = 0.f;
    #pragma unroll 8
    for (int mm = 0; mm < 64; ++mm)
      acc = fmaf(piW3[k * 512 + mm * 8 + b], iiW1[mm * 64 + col], acc);
    Bpack[gid] = f2bf_rne(acc);
  } else if (gid < 32832) {
    int c = gid - 32768;
    float acc = pib2[c];
    for (int k = 0; k < 64; ++k) acc = fmaf(pib1[k], piW2[k * 64 + c], acc);
    b12[c] = acc;
  } else if (gid < 36928) {
    int g2 = gid - 32832;
    int j = g2 & 7;
    int lane = (g2 >> 3) & 63;
    int ct = (g2 >> 9) & 3;
    int ks = g2 >> 11;
    int kidx = ks * 32 + ((lane >> 4) << 3) + j;
    int col = ct * 16 + (lane & 15);
    W2pack[g2] = f2bf_rne(iiW2[kidx * 64 + col]);
  }
}

// ---------- D2: single-dispatch exclusive scan (block b scans chunk b; redundant base)
__global__ __launch_bounds__(1024) void scan_kernel(
    const int* __restrict__ counts, int* __restrict__ cursors) {
  __shared__ int buf[1024];
  __shared__ int red[16];
  int b = blockIdx.x, tid = threadIdx.x;
  int idx = b * 1024 + tid;
  int v = counts[idx];
  buf[tid] = v;
  int partial = 0;
  for (int i = tid; i < b * 1024; i += 1024) partial += counts[i];
  #pragma unroll
  for (int off = 32; off >= 1; off >>= 1) partial += __shfl_down(partial, off, 64);
  if ((tid & 63) == 0) red[tid >> 6] = partial;
  __syncthreads();
  for (int off = 1; off < 1024; off <<= 1) {
    int t = (tid >= off) ? buf[tid - off] : 0;
    __syncthreads();
    buf[tid] += t;
    __syncthreads();
  }
  int base = 0;
  #pragma unroll
  for (int i = 0; i < 16; ++i) base += red[i];
  cursors[idx] = base + buf[tid] - v;
}

// ---------- D3: node MLP (MFMA) fused with sort-scatter (512 threads).
// blocks [0,391): node -> qa,qb ; blocks [391,1954): scatter edges into j-sorted order
__global__ __launch_bounds__(512) void node_scatter_kernel(
    const float* __restrict__ p,
    const int* __restrict__ idx_i, const int* __restrict__ idx_j,
    const float* __restrict__ ppW1, const float* __restrict__ ppb1,
    const float* __restrict__ ppW2, const float* __restrict__ ppb2,
    const float* __restrict__ piW1, const float* __restrict__ piW2,
    int* __restrict__ cursors,
    float* __restrict__ qa, float* __restrict__ qb,
    int2* __restrict__ sorted_ij, int* __restrict__ sorted_e) {
  int bid = blockIdx.x;
  int tid = threadIdx.x;

  if (bid >= 391) {  // ---------------- scatter
    int e = (bid - 391) * 512 + tid;
    if (e < N_EDGES) {
      int j = idx_j[e];
      int pos = atomicAdd(&cursors[j], 1);
      sorted_ij[pos] = make_int2(idx_i[e], j);
      sorted_e[pos] = e;
    }
    return;
  }

  // ---------------- node (MFMA)
  __shared__ __align__(16) unsigned short sBpk[2][4096];  // 16 KB
  __shared__ __align__(16) unsigned short sAct[2][8192];  // 32 KB

  int w = tid >> 6, l = tid & 63;
  int m = l & 15;
  int nb0 = bid * 128;

  for (int t = tid; t < 2048; t += 512) {
    int row = t >> 4, q = t & 15;
    int g = nb0 + row;
    float4 v = make_float4(0.f, 0.f, 0.f, 0.f);
    if (g < N_NODES) v = ((const float4*)p)[g * 16 + q];
    unsigned u0, u1;
    asm("v_cvt_pk_bf16_f32 %0, %1, %2" : "=v"(u0) : "v"(v.x), "v"(v.y));
    asm("v_cvt_pk_bf16_f32 %0, %1, %2" : "=v"(u1) : "v"(v.z), "v"(v.w));
    int sw = (row & 7) << 3;
    *(uint2*)(&sAct[0][row * 64 + ((q * 4) ^ sw)]) = make_uint2(u0, u1);
  }
  packW(ppW1, sBpk[0], tid);
  packW(ppW2, sBpk[1], tid);
  __syncthreads();

  f32x4 acc[4];
  // A: h = tanh(X@ppW1 + b1) -> sAct[1]
  #pragma unroll
  for (int ct = 0; ct < 4; ++ct) {
    float bv = ppb1[ct * 16 + m];
    acc[ct] = (f32x4){bv, bv, bv, bv};
  }
  mfma_gemm(sAct[0], sBpk[0], w, l, acc);
  store_act(sAct[1], w, l, acc, true);
  __syncthreads();

  // B: p1 = h@ppW2 + b2 -> sAct[0]
  #pragma unroll
  for (int ct = 0; ct < 4; ++ct) {
    float bv = ppb2[ct * 16 + m];
    acc[ct] = (f32x4){bv, bv, bv, bv};
  }
  mfma_gemm(sAct[1], sBpk[1], w, l, acc);
  store_act(sAct[0], w, l, acc, false);
  __syncthreads();

  packW(piW1, sBpk[0], tid);
  packW(piW2, sBpk[1], tid);
  __syncthreads();

  // C: t1 = p1@piW1a -> sAct[1]
  #pragma unroll
  for (int ct = 0; ct < 4; ++ct) acc[ct] = (f32x4){0.f, 0.f, 0.f, 0.f};
  mfma_gemm(sAct[0], sBpk[0], w, l, acc);
  store_act(sAct[1], w, l, acc, false);
  __syncthreads();

  // E: qa = t1@piW2 -> global ; repack slot0 = piW1b
  #pragma unroll
  for (int ct = 0; ct < 4; ++ct) acc[ct] = (f32x4){0.f, 0.f, 0.f, 0.f};
  mfma_gemm(sAct[1], sBpk[1], w, l, acc);
  {
    int s = l >> 4;
    #pragma unroll
    for (int ct = 0; ct < 4; ++ct)
      #pragma unroll
      for (int r = 0; r < 4; ++r) {
        int rg = nb0 + w * 16 + s * 4 + r;
        if (rg < N_NODES) qa[(size_t)rg * 64 + ct * 16 + m] = acc[ct][r];
      }
  }
  packW(piW1 + 4096, sBpk[0], tid);
  __syncthreads();

  // D: t2 = p1@piW1b -> sAct[1]
  #pragma unroll
  for (int ct = 0; ct < 4; ++ct) acc[ct] = (f32x4){0.f, 0.f, 0.f, 0.f};
  mfma_gemm(sAct[0], sBpk[0], w, l, acc);
  store_act(sAct[1], w, l, acc, false);
  __syncthreads();

  // F: qb = t2@piW2 -> global
  #pragma unroll
  for (int ct = 0; ct < 4; ++ct) acc[ct] = (f32x4){0.f, 0.f, 0.f, 0.f};
  mfma_gemm(sAct[1], sBpk[1], w, l, acc);
  {
    int s = l >> 4;
    #pragma unroll
    for (int ct = 0; ct < 4; ++ct)
      #pragma unroll
      for (int r = 0; r < 4; ++r) {
        int rg = nb0 + w * 16 + s * 4 + r;
        if (rg < N_NODES) qb[(size_t)rg * 64 + ct * 16 + m] = acc[ct][r];
      }
  }
}

// ---------- D4: edge (j-sorted), 1024 threads = 16 waves, 256 edges/block.
// T14 async-stage: Bpack global loads + sorted_e/basis loads issued at entry,
// LDS writes deferred past the h2-extract barrier.
__global__ __launch_bounds__(1024, 8) void edge_kernel(
    const int2* __restrict__ sorted_ij, const int* __restrict__ sorted_e,
    const float* __restrict__ basis,
    const float* __restrict__ qa, const float* __restrict__ qb,
    const float* __restrict__ b12,
    const unsigned short* __restrict__ Bpack,
    const unsigned short* __restrict__ W2pack,
    const float* __restrict__ iib1, const float* __restrict__ iib2,
    float* __restrict__ out) {
  __shared__ __align__(16) unsigned short sB[32768];  // 64 KB
  float* sH2 = (float*)sB;
  unsigned short* sT = sB;
  float* sF = (float*)sB;

  int tid = threadIdx.x;
  int e0 = blockIdx.x * 256;
  int w = tid >> 6, l = tid & 63;
  int m = l & 15, s = l >> 4;
  int eloc = w * 16 + m;
  int swz = (eloc & 7) << 3;

  // ---- issue long-latency loads first (T14): Bpack (L2) + basis (random)
  const uint4* gB = (const uint4*)Bpack;
  uint4 bp0 = gB[tid];
  uint4 bp1 = gB[tid + 1024];
  uint4 bp2 = gB[tid + 2048];
  uint4 bp3 = gB[tid + 3072];
  int eorig = sorted_e[e0 + eloc];
  const float4* bpt = (const float4*)(basis + (size_t)eorig * 8);
  float4 bas01 = bpt[0];
  float4 bas23 = bpt[1];

  // ---- phase 0: gather h2 into LDS (f32, XOR-swizzled). qb rows L1-hot (sorted j).
  for (int t = tid; t < 4096; t += 1024) {
    int e = t >> 4, q = t & 15;
    int2 se = sorted_ij[e0 + e];
    float4 va = ((const float4*)qa)[se.x * 16 + q];
    float4 vb = ((const float4*)qb)[se.y * 16 + q];
    float4 vc = ((const float4*)b12)[q];
    float4 h;
    h.x = va.x + vb.x + vc.x;
    h.y = va.y + vb.y + vc.y;
    h.z = va.z + vb.z + vc.z;
    h.w = va.w + vb.w + vc.w;
    int dw = e * 64 + ((q * 4) ^ ((e & 7) << 3));
    *((float4*)(sH2 + dw)) = h;
  }
  __syncthreads();

  float h2r[16];
  #pragma unroll
  for (int t = 0; t < 16; ++t) h2r[t] = sH2[eloc * 64 + ((t * 4 + s) ^ swz)];

  float bas[8];
  bas[0] = bas01.x; bas[1] = bas01.y; bas[2] = bas01.z; bas[3] = bas01.w;
  bas[4] = bas23.x; bas[5] = bas23.y; bas[6] = bas23.z; bas[7] = bas23.w;
  __syncthreads();

  // ---- write prefetched Bpack into LDS
  {
    uint4* d = (uint4*)sB;
    d[tid] = bp0;
    d[tid + 1024] = bp1;
    d[tid + 2048] = bp2;
    d[tid + 3072] = bp3;
  }
  __syncthreads();

  f32x4 c0, c1, c2, c3;
  {
    float v0 = iib1[m], v1 = iib1[16 + m], v2 = iib1[32 + m], v3 = iib1[48 + m];
    c0 = (f32x4){v0, v0, v0, v0};
    c1 = (f32x4){v1, v1, v1, v1};
    c2 = (f32x4){v2, v2, v2, v2};
    c3 = (f32x4){v3, v3, v3, v3};
  }

  // ---- main K-loop: 16 K-steps x 4 col-tiles, rne-bf16 A = 64 MFMA/wave
  const bf16x8* Bl = (const bf16x8*)sB;
  #pragma unroll
  for (int ks = 0; ks < 16; ++ks) {
    bf16x8 B0 = Bl[(ks * 4 + 0) * 64 + l];
    bf16x8 B1 = Bl[(ks * 4 + 1) * 64 + l];
    bf16x8 B2 = Bl[(ks * 4 + 2) * 64 + l];
    bf16x8 B3 = Bl[(ks * 4 + 3) * 64 + l];
    float hv = h2r[ks];
    union { unsigned u[4]; bf16x8 v; } A;
    #pragma unroll
    for (int j = 0; j < 4; ++j) {
      float p0 = hv * bas[2 * j];
      float p1 = hv * bas[2 * j + 1];
      asm("v_cvt_pk_bf16_f32 %0, %1, %2" : "=v"(A.u[j]) : "v"(p0), "v"(p1));
    }
    c0 = __builtin_amdgcn_mfma_f32_16x16x32_bf16(A.v, B0, c0, 0, 0, 0);
    c1 = __builtin_amdgcn_mfma_f32_16x16x32_bf16(A.v, B1, c1, 0, 0, 0);
    c2 = __builtin_amdgcn_mfma_f32_16x16x32_bf16(A.v, B2, c2, 0, 0, 0);
    c3 = __builtin_amdgcn_mfma_f32_16x16x32_bf16(A.v, B3, c3, 0, 0, 0);
  }
  __syncthreads();

  // ---- tanh -> t tile (bf16). D layout: col = ct*16+m, row(local) = s*4+r
  #pragma unroll
  for (int r = 0; r < 4; ++r) {
    int row = w * 16 + s * 4 + r;
    sT[row * 72 + 0 * 16 + m] = f2bf_rne(fast_tanh(c0[r]));
    sT[row * 72 + 1 * 16 + m] = f2bf_rne(fast_tanh(c1[r]));
    sT[row * 72 + 2 * 16 + m] = f2bf_rne(fast_tanh(c2[r]));
    sT[row * 72 + 3 * 16 + m] = f2bf_rne(fast_tanh(c3[r]));
  }
  __syncthreads();

  // ---- second GEMM: i2 = t @ ii_W2 + ii_b2 (K=64: 2 K-steps x 4 col-tiles)
  f32x4 d0, d1, d2, d3;
  {
    float v0 = iib2[m], v1 = iib2[16 + m], v2 = iib2[32 + m], v3 = iib2[48 + m];
    d0 = (f32x4){v0, v0, v0, v0};
    d1 = (f32x4){v1, v1, v1, v1};
    d2 = (f32x4){v2, v2, v2, v2};
    d3 = (f32x4){v3, v3, v3, v3};
  }
  const bf16x8* Wl = (const bf16x8*)W2pack;
  #pragma unroll
  for (int ks = 0; ks < 2; ++ks) {
    bf16x8 Af = *(const bf16x8*)(sT + eloc * 72 + ks * 32 + s * 8);
    d0 = __builtin_amdgcn_mfma_f32_16x16x32_bf16(Af, Wl[(ks * 4 + 0) * 64 + l], d0, 0, 0, 0);
    d1 = __builtin_amdgcn_mfma_f32_16x16x32_bf16(Af, Wl[(ks * 4 + 1) * 64 + l], d1, 0, 0, 0);
    d2 = __builtin_amdgcn_mfma_f32_16x16x32_bf16(Af, Wl[(ks * 4 + 2) * 64 + l], d2, 0, 0, 0);
    d3 = __builtin_amdgcn_mfma_f32_16x16x32_bf16(Af, Wl[(ks * 4 + 3) * 64 + l], d3, 0, 0, 0);
  }

  // ---- phase 3: run-aggregated scatter (two 128-edge halves through LDS)
  #pragma unroll
  for (int h = 0; h < 2; ++h) {
    __syncthreads();
    if ((w >> 3) == h) {
      int wl = w & 7;
      #pragma unroll
      for (int r = 0; r < 4; ++r) {
        int row = wl * 16 + s * 4 + r;
        sF[row * 68 + 0  + m] = d0[r];
        sF[row * 68 + 16 + m] = d1[r];
        sF[row * 68 + 32 + m] = d2[r];
        sF[row * 68 + 48 + m] = d3[r];
      }
    }
    __syncthreads();
    {
      int base_e = e0 + h * 128 + w * 8;
      float acc = sF[(w * 8) * 68 + l];
      int cur_j = sorted_ij[base_e].y;
      #pragma unroll
      for (int rr = 1; rr < 8; ++rr) {
        int nj = sorted_ij[base_e + rr].y;
        float v = sF[(w * 8 + rr) * 68 + l];
        if (nj == cur_j) {
          acc += v;
        } else {
          atomicAdd(&out[(size_t)cur_j * 64 + l], acc);
          acc = v;
          cur_j = nj;
        }
      }
      atomicAdd(&out[(size_t)cur_j * 64 + l], acc);
    }
  }
}

extern "C" void kernel_launch(void* const* d_in, const int* in_sizes, int n_in,
                              void* d_out, int out_size, void* d_ws, size_t ws_size,
                              hipStream_t stream) {
  const float* p     = (const float*)d_in[0];
  const int*   idx_i = (const int*)d_in[1];
  const int*   idx_j = (const int*)d_in[2];
  const float* basis = (const float*)d_in[3];
  const float* ppW1  = (const float*)d_in[4];
  const float* ppb1  = (const float*)d_in[5];
  const float* ppW2  = (const float*)d_in[6];
  const float* ppb2  = (const float*)d_in[7];
  const float* piW1  = (const float*)d_in[8];
  const float* pib1  = (const float*)d_in[9];
  const float* piW2  = (const float*)d_in[10];
  const float* pib2  = (const float*)d_in[11];
  const float* piW3  = (const float*)d_in[12];
  const float* iiW1  = (const float*)d_in[13];
  const float* iib1  = (const float*)d_in[14];
  const float* iiW2  = (const float*)d_in[15];
  const float* iib2  = (const float*)d_in[16];

  float* ws  = (float*)d_ws;
  float* qa  = ws;                          // 3,200,000 f
  float* qb  = ws + 3200000;                // 3,200,000 f
  float* b12 = ws + 6400000;                // 64 f
  unsigned short* Bpack  = (unsigned short*)(ws + 6400064);   // 32768 bf16 (16384 f)
  unsigned short* W2pack = (unsigned short*)(ws + 6416448);   // 4096 bf16 (2048 f)
  int* counts    = (int*)(ws + 6418496);    // NPAD ints
  int* cursors   = (int*)(ws + 6468672);    // NPAD ints
  int2* sorted_ij = (int2*)(ws + 6518848);  // 800000 int2 (8B-aligned)
  int* sorted_e   = (int*)(ws + 8118848);   // 800000 ints (end ~35.7 MB)

  hipMemsetAsync(d_out, 0, (size_t)out_size * sizeof(float), stream);
  hipMemsetAsync(counts, 0, (size_t)NPAD * sizeof(int), stream);
  hist_prep_kernel<<<1636, 512, 0, stream>>>(idx_j, piW2, pib1, pib2,
                                             piW3, iiW1, iiW2,
                                             counts, b12, Bpack, W2pack);
  scan_kernel<<<49, 1024, 0, stream>>>(counts, cursors);
  node_scatter_kernel<<<1954, 512, 0, stream>>>(p, idx_i, idx_j,
                                                ppW1, ppb1, ppW2, ppb2,
                                                piW1, piW2, cursors,
                                                qa, qb, sorted_ij, sorted_e);
  edge_kernel<<<3125, 1024, 0, stream>>>(sorted_ij, sorted_e, basis,
                                         qa, qb, b12, Bpack, W2pack,
                                         iib1, iib2, (float*)d_out);
}